// Round 10
// baseline (30794.370 us; speedup 1.0000x reference)
//
#include <hip/hip_runtime.h>
#include <hip/hip_cooperative_groups.h>

namespace cg = cooperative_groups;

// CRF forward algorithm on MI355X — round 10.
// v_t = diag(2^feat) * (E @ v_{t-1}) in the linear domain, E = exp(trans).
// Compute (proven r5-r9, absmax 0.0): E as f16 in 128KB dynamic LDS, matvec
//   via v_dot2_f32_f16 on conflict-free b128 reads; p staged normalized f16.
// Sync: r6-r9 exhausted the hand-rolled relaxed-polling space (plain/system/
//   fenced/RMW publishes all intermittently invisible to remote pollers ->
//   phantom-NaN timeout). The only configurations that ever worked had full
//   release/acquire (wbl2+inv) on both sides (r5) — so use the runtime's
//   grid-wide barrier: hipLaunchCooperativeKernel + cg::grid.sync() per step,
//   double-buffered p. No polling, no timeouts, uniform control flow,
//   bitwise-deterministic output.

#define T_STEPS 1024
#define NRULES  4095
#define NTAGS   4096
#define L2E     1.4426950408889634f
#define LN2     0.69314718055994530942

typedef __fp16 h2 __attribute__((ext_vector_type(2)));

#if __has_builtin(__builtin_amdgcn_fdot2)
#define FDOT2(a, b, c) __builtin_amdgcn_fdot2((a), (b), (c), false)
#else
__device__ __forceinline__ float FDOT2(h2 a, h2 b, float c) {
  return c + (float)a[0] * (float)b[0] + (float)a[1] * (float)b[1];
}
#endif

// ws layout: buf0 (4096 f32) | buf1 (4096 f32) | lp (1 f32)
#define LP_OFF (2 * NTAGS)

// Supervised path score (unchanged from the absmax==0 versions).
__global__ void crf_logprob(const float* __restrict__ feats,
                            const float* __restrict__ trans,
                            const int* __restrict__ tags,
                            float* __restrict__ lp) {
  int t = threadIdx.x;
  int prev = (t == 0) ? 0 : tags[t - 1];
  int nxt  = tags[t];
  int er = prev - 1; if (er < 0) er += NRULES;
  float v = feats[(size_t)t * NRULES + er] + trans[(size_t)nxt * NTAGS + prev];
  #pragma unroll
  for (int d = 32; d; d >>= 1) v += __shfl_xor(v, d, 64);
  __shared__ float sb[16];
  if ((t & 63) == 0) sb[t >> 6] = v;
  __syncthreads();
  if (t == 0) {
    float s = 0.f;
    #pragma unroll
    for (int i = 0; i < 16; ++i) s += sb[i];
    lp[0] = s;
  }
}

// Persistent cooperative scan. Grid 256 x block 512 (8 waves), 1 block/CU.
// Wave w owns rows {2w, 2w+1} of its block's 16 tags; lane l covers the
// 16B chunk at byte offset 1024k + 16l, k=0..7 of each 4096-wide f16 dot.
__launch_bounds__(512, 2)
__global__ void crf_scan(const float* __restrict__ feats,
                         const float* __restrict__ trans,
                         float* __restrict__ ws,
                         float* __restrict__ out)
{
  cg::grid_group grid = cg::this_grid();

  extern __shared__ __align__(16) char dynsm[]; // [0,131072): E f16; then p f16
  __fp16* const PS = (__fp16*)(dynsm + 131072);

  float* const buf0     = ws;
  float* const buf1     = ws + NTAGS;
  const float* const lp = ws + LP_OFF;

  const int g    = blockIdx.x;
  const int tid  = threadIdx.x;
  const int wave = tid >> 6;
  const int lane = tid & 63;
  const int tagbase = g * 16 + 2 * wave;

  __shared__ float wred[8];

  // ---- one-time: E[r][c] = (f16) exp(trans[g*16+r][c]) into LDS ----
  // trans row 0 is all -1e4 -> exp2 underflows to +0 -> p[0] stays 0. [exact]
  {
    const size_t base = (size_t)(g * 16) * NTAGS;
    for (int i = tid; i < 16 * 2048; i += 512) {
      const int row = i >> 11, pr = i & 2047;
      const float2 v = *reinterpret_cast<const float2*>(
          trans + base + (size_t)row * NTAGS + 2 * pr);
      h2 e = __builtin_amdgcn_cvt_pkrtz(__builtin_amdgcn_exp2f(v.x * L2E),
                                        __builtin_amdgcn_exp2f(v.y * L2E));
      *reinterpret_cast<h2*>(dynsm + row * 8192 + 4 * pr) = e;
    }
  }

  // ---- init my 16 entries of buf0 = p_0 = [1, 0, 0, ...] ----
  // Every launch rewrites all 4096 entries (256 blocks x 16): no stale state.
  if (tid < 16) buf0[g * 16 + tid] = (g == 0 && tid == 0) ? 1.0f : 0.0f;

  __syncthreads();
  grid.sync();                      // buf0 + LDS E visible everywhere

  double Racc = 0.0;  // sum of log2(per-step max); identical on all threads

  for (int t = 1; t <= T_STEPS; ++t) {
    const float* pprev = (t & 1) ? buf0 : buf1;
    float*       pnext = (t & 1) ? buf1 : buf0;

    // ---- load p_{t-1} (fresh after grid.sync), block max ----
    float pv[8];
    #pragma unroll
    for (int i = 0; i < 8; ++i) pv[i] = pprev[tid + 512 * i];

    float mloc = 0.0f;  // p >= 0
    #pragma unroll
    for (int i = 0; i < 8; ++i) mloc = fmaxf(mloc, pv[i]);
    #pragma unroll
    for (int d = 32; d; d >>= 1) mloc = fmaxf(mloc, __shfl_xor(mloc, d, 64));
    if (lane == 0) wred[wave] = mloc;

    // feats for my 2 rows (read-only input, normal cached loads)
    const int fi0 = (tagbase == 0) ? 0 : tagbase - 1;
    const float fe0 = feats[(size_t)(t - 1) * NRULES + fi0] * L2E;
    const float fe1 = feats[(size_t)(t - 1) * NRULES + tagbase] * L2E;

    __syncthreads();   // B0: wred ready

    float pmax = wred[0];
    #pragma unroll
    for (int i = 1; i < 8; ++i) pmax = fmaxf(pmax, wred[i]);
    const float rprev = __builtin_amdgcn_logf(pmax);   // log2(max p_{t-1})
    const float inv   = __builtin_amdgcn_rcpf(pmax);   // pmax > 0 always
    Racc += (double)rprev;

    // ---- stage q = p/pmax as f16 into PS (q in [0,1] -> no overflow)
    #pragma unroll
    for (int i = 0; i < 8; ++i)
      PS[tid + 512 * i] = (__fp16)(pv[i] * inv);

    __syncthreads();   // B1: PS ready

    // ---- matvec: a_r = sum_j E[r][j] * q[j]; conflict-free b128 reads ----
    float a0 = 0.f, a1 = 0.f;
    const char* Er0 = dynsm + (2 * wave) * 8192;
    const char* Er1 = Er0 + 8192;
    const char* PSb = (const char*)PS;
    #pragma unroll
    for (int k = 0; k < 8; ++k) {
      const int off = 1024 * k + 16 * lane;
      const float4 pq = *reinterpret_cast<const float4*>(PSb + off);
      const float4 e0 = *reinterpret_cast<const float4*>(Er0 + off);
      const float4 e1 = *reinterpret_cast<const float4*>(Er1 + off);
      const h2 p0 = __builtin_bit_cast(h2, pq.x), p1 = __builtin_bit_cast(h2, pq.y);
      const h2 p2 = __builtin_bit_cast(h2, pq.z), p3 = __builtin_bit_cast(h2, pq.w);
      a0 = FDOT2(__builtin_bit_cast(h2, e0.x), p0, a0);
      a0 = FDOT2(__builtin_bit_cast(h2, e0.y), p1, a0);
      a0 = FDOT2(__builtin_bit_cast(h2, e0.z), p2, a0);
      a0 = FDOT2(__builtin_bit_cast(h2, e0.w), p3, a0);
      a1 = FDOT2(__builtin_bit_cast(h2, e1.x), p0, a1);
      a1 = FDOT2(__builtin_bit_cast(h2, e1.y), p1, a1);
      a1 = FDOT2(__builtin_bit_cast(h2, e1.z), p2, a1);
      a1 = FDOT2(__builtin_bit_cast(h2, e1.w), p3, a1);
    }
    #pragma unroll
    for (int d = 32; d; d >>= 1) {
      a0 += __shfl_xor(a0, d, 64);
      a1 += __shfl_xor(a1, d, 64);
    }

    // y = fe + log2(a') (a' already normalized); publish p_t = 2^y.
    // a >= 0 always; a==0 -> 2^-inf = +0 (never NaN / never inf).
    if (lane < 2) {
      const float y = (lane == 0) ? (fe0 + __builtin_amdgcn_logf(a0))
                                  : (fe1 + __builtin_amdgcn_logf(a1));
      pnext[tagbase + lane] = __builtin_amdgcn_exp2f(y);
    }

    grid.sync();       // publishes visible; pprev free for reuse next step
  }

  // ---- finalization: Z = ln2*(log2(sum p_T) + Racc); out = Z - logprob ----
  // p_T is in buf0 (t=1024 wrote pnext=buf0); last grid.sync made it visible.
  if (g == 0) {
    const float* pT = buf0;
    float s = 0.f;
    #pragma unroll
    for (int i = 0; i < 8; ++i) s += pT[tid + 512 * i];
    #pragma unroll
    for (int d = 32; d; d >>= 1) s += __shfl_xor(s, d, 64);
    __syncthreads();
    if (lane == 0) wred[wave] = s;
    __syncthreads();
    if (tid == 0) {
      float tot = 0.f;
      #pragma unroll
      for (int i = 0; i < 8; ++i) tot += wred[i];
      const double Z2 = (double)__builtin_amdgcn_logf(tot) + Racc;
      out[0] = (float)(LN2 * Z2 - (double)lp[0]);
    }
  }
}

extern "C" void kernel_launch(void* const* d_in, const int* in_sizes, int n_in,
                              void* d_out, int out_size, void* d_ws, size_t ws_size,
                              hipStream_t stream) {
  const float* feats = (const float*)d_in[0];   // (1024, 1, 4095) f32
  const float* trans = (const float*)d_in[1];   // (4096, 4096) f32
  const int*   tags  = (const int*)d_in[2];     // (1024,) i32
  float* out = (float*)d_out;                   // (1,) f32
  float* ws  = (float*)d_ws;

  (void)hipFuncSetAttribute(reinterpret_cast<const void*>(crf_scan),
                            hipFuncAttributeMaxDynamicSharedMemorySize, 139264);

  crf_logprob<<<1, 1024, 0, stream>>>(feats, trans, tags, ws + LP_OFF);

  void* args[] = { (void*)&feats, (void*)&trans, (void*)&ws, (void*)&out };
  (void)hipLaunchCooperativeKernel(reinterpret_cast<void*>(crf_scan),
                                   dim3(256), dim3(512), args, 139264, stream);
}

// Round 11
// 5045.930 us; speedup vs baseline: 6.1028x; 6.1028x over previous
//
#include <hip/hip_runtime.h>
#include <hip/hip_cooperative_groups.h>

namespace cg = cooperative_groups;

// CRF forward algorithm on MI355X — round 11.
// v_t = diag(2^feat) * (E @ v_{t-1}) in the linear domain, E = exp(trans).
// Compute (proven r5-r10, absmax 0.0): E as f16 in 128KB dynamic LDS, matvec
//   via v_dot2_f32_f16 on conflict-free b128 reads; p staged normalized f16.
// Sync: COOPERATIVE LAUNCH for guaranteed co-residency + the cheap NaN-
//   sentinel ring as the per-step barrier. r10 (cg::grid.sync per step) was
//   correct but 30us/step = 30.8ms total. Diagnosis of r6-r9's intermittent
//   stalls, revised: at 139KB LDS (1 block/CU), a NON-cooperative launch can
//   dispatch a block late; 255 resident spinners then pin every CU and the
//   straggler never schedules -> deadlock. That explains why store flavor
//   (plain/system/fence/RMW, r6-r9) made no difference, and why r1-r3
//   (17.9KB LDS, multi-block/CU) never failed. The ring protocol itself was
//   absmax-0.0-correct whenever all blocks ran. Cooperative launch removes
//   the scheduling hazard; the ring gives ~1.5us steps instead of 30us.
//   grid.sync() is used exactly once (after ring init).

#define T_STEPS 1024
#define NRULES  4095
#define NTAGS   4096
#define RING    8
#define L2E     1.4426950408889634f
#define LN2     0.69314718055994530942

typedef __fp16 h2 __attribute__((ext_vector_type(2)));

#if __has_builtin(__builtin_amdgcn_fdot2)
#define FDOT2(a, b, c) __builtin_amdgcn_fdot2((a), (b), (c), false)
#else
__device__ __forceinline__ float FDOT2(h2 a, h2 b, float c) {
  return c + (float)a[0] * (float)b[0] + (float)a[1] * (float)b[1];
}
#endif

// Ring accesses: agent-scope relaxed (validated by r1-r3's absmax-0.0 runs).
__device__ __forceinline__ float ld_ring(const float* p) {
  return __hip_atomic_load(p, __ATOMIC_RELAXED, __HIP_MEMORY_SCOPE_AGENT);
}
__device__ __forceinline__ void st_ring(float* p, float v) {
  __hip_atomic_store(p, v, __ATOMIC_RELAXED, __HIP_MEMORY_SCOPE_AGENT);
}

// ws layout: pring (8*4096 f32) | lp (1 f32)
#define LP_OFF (RING * NTAGS)

// Supervised path score (unchanged from the absmax==0 versions).
__global__ void crf_logprob(const float* __restrict__ feats,
                            const float* __restrict__ trans,
                            const int* __restrict__ tags,
                            float* __restrict__ lp) {
  int t = threadIdx.x;
  int prev = (t == 0) ? 0 : tags[t - 1];
  int nxt  = tags[t];
  int er = prev - 1; if (er < 0) er += NRULES;
  float v = feats[(size_t)t * NRULES + er] + trans[(size_t)nxt * NTAGS + prev];
  #pragma unroll
  for (int d = 32; d; d >>= 1) v += __shfl_xor(v, d, 64);
  __shared__ float sb[16];
  if ((t & 63) == 0) sb[t >> 6] = v;
  __syncthreads();
  if (t == 0) {
    float s = 0.f;
    #pragma unroll
    for (int i = 0; i < 16; ++i) s += sb[i];
    lp[0] = s;
  }
}

// Persistent cooperative scan. Grid 256 x block 512 (8 waves), 1 block/CU.
// Wave w owns rows {2w, 2w+1} of its block's 16 tags; lane l covers the
// 16B chunk at byte offset 1024k + 16l, k=0..7 of each 4096-wide f16 dot.
__launch_bounds__(512, 2)
__global__ void crf_scan(const float* __restrict__ feats,
                         const float* __restrict__ trans,
                         float* __restrict__ ws,
                         float* __restrict__ out)
{
  cg::grid_group grid = cg::this_grid();

  extern __shared__ __align__(16) char dynsm[]; // [0,131072): E f16; then p f16
  __fp16* const PS = (__fp16*)(dynsm + 131072);

  float* const pring    = ws;
  const float* const lp = ws + LP_OFF;

  const int g    = blockIdx.x;
  const int tid  = threadIdx.x;
  const int wave = tid >> 6;
  const int lane = tid & 63;
  const int tagbase = g * 16 + 2 * wave;

  __shared__ float wred[8];
  __shared__ int giveup;
  if (tid == 0) giveup = 0;

  // ---- one-time: E[r][c] = (f16) exp(trans[g*16+r][c]) into LDS ----
  // trans row 0 is all -1e4 -> exp2 underflows to +0 -> p[0] stays 0. [exact]
  {
    const size_t base = (size_t)(g * 16) * NTAGS;
    for (int i = tid; i < 16 * 2048; i += 512) {
      const int row = i >> 11, pr = i & 2047;
      const float2 v = *reinterpret_cast<const float2*>(
          trans + base + (size_t)row * NTAGS + 2 * pr);
      h2 e = __builtin_amdgcn_cvt_pkrtz(__builtin_amdgcn_exp2f(v.x * L2E),
                                        __builtin_amdgcn_exp2f(v.y * L2E));
      *reinterpret_cast<h2*>(dynsm + row * 8192 + 4 * pr) = e;
    }
  }

  // ---- ring init: each block owns its 16 tags in every slot.
  // slot 0 = p_0 = [1,0,...]; slots 1..7 = NaN. Rewritten every launch.
  if (tid < 16) {
    #pragma unroll
    for (int s = 0; s < RING; ++s) {
      float v = (s == 0) ? ((g == 0 && tid == 0) ? 1.0f : 0.0f)
                         : __builtin_nanf("");
      st_ring(&pring[s * NTAGS + g * 16 + tid], v);
    }
  }

  __syncthreads();
  grid.sync();          // ring init + LDS E visible; all blocks co-resident

  double Racc = 0.0;  // sum of log2(per-step max); identical on all threads

  for (int t = 1; t <= T_STEPS; ++t) {
    const int sprev = (t - 1) & (RING - 1);
    const int scur  = t & (RING - 1);
    const float* pprev = pring + sprev * NTAGS;

    __syncthreads();   // B2: PS consumed last step; publish stores drained
                       //     (implicit vmcnt0); giveup visible
    if (giveup) break;

    // ---- prefetch + poll p_{t-1}: values ARE the flags (NaN = not ready).
    float pv[8];
    #pragma unroll
    for (int i = 0; i < 8; ++i) pv[i] = ld_ring(&pprev[tid + 512 * i]);
    {
      int rounds = 0;
      for (;;) {
        bool bad = false;
        #pragma unroll
        for (int i = 0; i < 8; ++i) bad |= (pv[i] != pv[i]);
        if (__ballot(bad) == 0ull) break;
        if (++rounds > (1 << 21)) { giveup = 1; break; }  // fail loud, not hang
        __builtin_amdgcn_s_sleep(1);
        #pragma unroll
        for (int i = 0; i < 8; ++i)
          if (pv[i] != pv[i]) pv[i] = ld_ring(&pprev[tid + 512 * i]);
      }
    }

    // ---- recycle slot t-2 to NaN (all readers provably past it: entering
    // step t required slot t-1 complete => every block finished step t-1,
    // i.e. finished polling slot t-2). Next write: step t+6 — 6 steps of
    // visibility margin before any poller depends on the NaN.
    if (t >= 2 && wave == 0 && lane < 16)
      st_ring(&pring[((t - 2) & (RING - 1)) * NTAGS + g * 16 + lane],
              __builtin_nanf(""));

    // ---- block max of p_{t-1}
    float mloc = 0.0f;  // p >= 0
    #pragma unroll
    for (int i = 0; i < 8; ++i) mloc = fmaxf(mloc, pv[i]);
    #pragma unroll
    for (int d = 32; d; d >>= 1) mloc = fmaxf(mloc, __shfl_xor(mloc, d, 64));
    if (lane == 0) wred[wave] = mloc;

    // feats for my 2 rows (read-only input, normal cached loads)
    const int fi0 = (tagbase == 0) ? 0 : tagbase - 1;
    const float fe0 = feats[(size_t)(t - 1) * NRULES + fi0] * L2E;
    const float fe1 = feats[(size_t)(t - 1) * NRULES + tagbase] * L2E;

    __syncthreads();   // B0: wred ready

    float pmax = wred[0];
    #pragma unroll
    for (int i = 1; i < 8; ++i) pmax = fmaxf(pmax, wred[i]);
    const float rprev = __builtin_amdgcn_logf(pmax);   // log2(max p_{t-1})
    const float inv   = __builtin_amdgcn_rcpf(pmax);   // pmax > 0 always
    Racc += (double)rprev;

    // ---- stage q = p/pmax as f16 into PS (q in [0,1] -> no overflow)
    #pragma unroll
    for (int i = 0; i < 8; ++i)
      PS[tid + 512 * i] = (__fp16)(pv[i] * inv);

    __syncthreads();   // B1: PS ready

    // ---- matvec: a_r = sum_j E[r][j] * q[j]; conflict-free b128 reads ----
    float a0 = 0.f, a1 = 0.f;
    const char* Er0 = dynsm + (2 * wave) * 8192;
    const char* Er1 = Er0 + 8192;
    const char* PSb = (const char*)PS;
    #pragma unroll
    for (int k = 0; k < 8; ++k) {
      const int off = 1024 * k + 16 * lane;
      const float4 pq = *reinterpret_cast<const float4*>(PSb + off);
      const float4 e0 = *reinterpret_cast<const float4*>(Er0 + off);
      const float4 e1 = *reinterpret_cast<const float4*>(Er1 + off);
      const h2 p0 = __builtin_bit_cast(h2, pq.x), p1 = __builtin_bit_cast(h2, pq.y);
      const h2 p2 = __builtin_bit_cast(h2, pq.z), p3 = __builtin_bit_cast(h2, pq.w);
      a0 = FDOT2(__builtin_bit_cast(h2, e0.x), p0, a0);
      a0 = FDOT2(__builtin_bit_cast(h2, e0.y), p1, a0);
      a0 = FDOT2(__builtin_bit_cast(h2, e0.z), p2, a0);
      a0 = FDOT2(__builtin_bit_cast(h2, e0.w), p3, a0);
      a1 = FDOT2(__builtin_bit_cast(h2, e1.x), p0, a1);
      a1 = FDOT2(__builtin_bit_cast(h2, e1.y), p1, a1);
      a1 = FDOT2(__builtin_bit_cast(h2, e1.z), p2, a1);
      a1 = FDOT2(__builtin_bit_cast(h2, e1.w), p3, a1);
    }
    #pragma unroll
    for (int d = 32; d; d >>= 1) {
      a0 += __shfl_xor(a0, d, 64);
      a1 += __shfl_xor(a1, d, 64);
    }

    // y = fe + log2(a') (a' already normalized); publish p_t = 2^y.
    // a >= 0 always; a==0 -> 2^-inf = +0 (never NaN).
    if (lane < 2) {
      const float y = (lane == 0) ? (fe0 + __builtin_amdgcn_logf(a0))
                                  : (fe1 + __builtin_amdgcn_logf(a1));
      st_ring(&pring[scur * NTAGS + tagbase + lane], __builtin_amdgcn_exp2f(y));
    }
  }

  __syncthreads();     // drain final publishes; exit together

  // ---- finalization: Z = ln2*(log2(sum p_T) + Racc); out = Z - logprob ----
  if (g == 0 && !giveup) {
    const float* pT = pring + (T_STEPS & (RING - 1)) * NTAGS;
    float pv[8];
    #pragma unroll
    for (int i = 0; i < 8; ++i) pv[i] = ld_ring(&pT[tid + 512 * i]);
    {
      int rounds = 0;
      for (;;) {
        bool bad = false;
        #pragma unroll
        for (int i = 0; i < 8; ++i) bad |= (pv[i] != pv[i]);
        if (__ballot(bad) == 0ull) break;
        if (++rounds > (1 << 21)) break;
        __builtin_amdgcn_s_sleep(1);
        #pragma unroll
        for (int i = 0; i < 8; ++i)
          if (pv[i] != pv[i]) pv[i] = ld_ring(&pT[tid + 512 * i]);
      }
    }
    float s = 0.f;
    #pragma unroll
    for (int i = 0; i < 8; ++i) s += pv[i];
    #pragma unroll
    for (int d = 32; d; d >>= 1) s += __shfl_xor(s, d, 64);
    if (lane == 0) wred[wave] = s;
    __syncthreads();
    if (tid == 0) {
      float tot = 0.f;
      #pragma unroll
      for (int i = 0; i < 8; ++i) tot += wred[i];
      const double Z2 = (double)__builtin_amdgcn_logf(tot) + Racc;
      out[0] = (float)(LN2 * Z2 - (double)lp[0]);
    }
  }
}

extern "C" void kernel_launch(void* const* d_in, const int* in_sizes, int n_in,
                              void* d_out, int out_size, void* d_ws, size_t ws_size,
                              hipStream_t stream) {
  const float* feats = (const float*)d_in[0];   // (1024, 1, 4095) f32
  const float* trans = (const float*)d_in[1];   // (4096, 4096) f32
  const int*   tags  = (const int*)d_in[2];     // (1024,) i32
  float* out = (float*)d_out;                   // (1,) f32
  float* ws  = (float*)d_ws;

  (void)hipFuncSetAttribute(reinterpret_cast<const void*>(crf_scan),
                            hipFuncAttributeMaxDynamicSharedMemorySize, 139264);

  crf_logprob<<<1, 1024, 0, stream>>>(feats, trans, tags, ws + LP_OFF);

  void* args[] = { (void*)&feats, (void*)&trans, (void*)&ws, (void*)&out };
  (void)hipLaunchCooperativeKernel(reinterpret_cast<void*>(crf_scan),
                                   dim3(256), dim3(512), args, 139264, stream);
}